// Round 1
// 95.491 us; speedup vs baseline: 1.0540x; 1.0540x over previous
//
#include <hip/hip_runtime.h>

// DistNet: out[n] = sigmoid((min_p ||x_n - p||^2 + alpha) / beta)
// beta = softplus(beta_raw), alpha = -beta*ln(1000)
// x: [65536,128] f32, points: [2048,128] f32, beta_raw: [1] f32, out: [65536] f32
//
// R7 design: points fp8 = 256 KB is L2-resident -> drop ALL LDS staging and
// per-stage barriers (R6's lockstep left waves ~95% idle; VALUBusy ~3%).
// Prep pre-swizzles points into MFMA fragment order so B is two coalesced
// 1KB global_load_dwordx4 per 16-pt tile, register double-buffered 2 tiles
// deep. 64 rows/wave (4 A-frags) halves B traffic; wave pairs split the
// point range (64 tiles each) to keep 2048 waves, min-combined via LDS.
// -||p||^2/2 is folded into the MFMA C-input (track max(x.p - pn/2)).

#define NROWS 65536
#define NPTS  2048
#define DIMS  128
#define LOG1000F 6.9077542789816375f

typedef __attribute__((ext_vector_type(8))) int i32x8;
typedef __attribute__((ext_vector_type(4))) float f32x4;

union AFrag { int d[8]; i32x8 v; };
union BFrag { uint4 u4[2]; i32x8 v; };

// --- pre-kernel: points f32 -> fp8 e4m3, PRE-SWIZZLED fragment order --------
// 16B unit u = (T*2+c)*64 + q*16 + m  holds point p = T*16+m, features
// k in [q*32+c*16, q*32+c*16+16). Main kernel B-load for tile T is then
// unit[(T*2+c)*64 + lane], i.e. two contiguous 1KB dwordx4 loads.
// Also writes ||p||^2.
__global__ __launch_bounds__(256) void prep_points_kernel(
    const float* __restrict__ pts, unsigned char* __restrict__ ptsf8,
    float* __restrict__ pnorm)
{
    int tid  = threadIdx.x;
    int lane = tid & 63;
    int w    = tid >> 6;
    int pt   = blockIdx.x * 4 + w;            // one wave per point
    const float2 v = *reinterpret_cast<const float2*>(
        pts + (size_t)pt * DIMS + lane * 2);  // features 2*lane, 2*lane+1
    int pk = __builtin_amdgcn_cvt_pk_fp8_f32(v.x, v.y, 0, false);
    int T  = pt >> 4, pm = pt & 15;
    int q  = lane >> 4;                       // (2*lane)>>5
    int c  = (lane >> 3) & 1;                 // ((2*lane)>>4)&1
    int j  = (lane & 7) * 2;                  // (2*lane)&15
    size_t dst = (size_t)((T * 2 + c) * 64 + q * 16 + pm) * 16 + j;
    *reinterpret_cast<unsigned short*>(ptsf8 + dst) =
        (unsigned short)(pk & 0xFFFF);
    float ss = v.x * v.x + v.y * v.y;
    ss += __shfl_xor(ss, 1, 64);
    ss += __shfl_xor(ss, 2, 64);
    ss += __shfl_xor(ss, 4, 64);
    ss += __shfl_xor(ss, 8, 64);
    ss += __shfl_xor(ss, 16, 64);
    ss += __shfl_xor(ss, 32, 64);
    if (lane == 0) pnorm[pt] = ss;
}

// --- main kernel ------------------------------------------------------------
// grid: NROWS/128 = 512 blocks x 256 threads (4 waves, 2 per CU).
// Wave pair (pairw) owns 64 rows; half=0 wave does point-tiles 0..63,
// half=1 wave does 64..127. No barriers in the main loop.
__global__ __launch_bounds__(256, 2) void distnet_main_kernel(
    const float* __restrict__ x, const unsigned char* __restrict__ ptsf8,
    const float* __restrict__ pnorm, const float* __restrict__ beta_raw,
    float* __restrict__ out)
{
    __shared__ __align__(16) float s_pn[NPTS];   // 8 KB: -0.5*||p||^2
    __shared__ float s_red[2][128];              // per-half partial max
    __shared__ float s_xn[128];                  // ||x||^2 per block row

    int tid = threadIdx.x;
    // stage -0.5*||p||^2 (MFMA C-input form) into LDS
    {
        const float4* p4 = reinterpret_cast<const float4*>(pnorm);
        float4* d4 = reinterpret_cast<float4*>(s_pn);
        float4 a = p4[tid], b = p4[tid + 256];
        d4[tid]       = make_float4(-.5f*a.x, -.5f*a.y, -.5f*a.z, -.5f*a.w);
        d4[tid + 256] = make_float4(-.5f*b.x, -.5f*b.y, -.5f*b.z, -.5f*b.w);
    }

    int wid   = tid >> 6, lane = tid & 63;
    int m     = lane & 15, q = lane >> 4;
    int pairw = wid >> 1, half = wid & 1;
    int rbase = blockIdx.x * 128 + pairw * 64;

    // A fragments: 4 row-tiles = 64 rows/wave; lane holds A[m][q*32+j].
    // Also per-row ||x||^2 into s_xn (written once by the half==0 wave).
    AFrag afrag[4];
#pragma unroll
    for (int t = 0; t < 4; ++t) {
        const float* xp = x + (size_t)(rbase + t * 16 + m) * DIMS + q * 32;
        float s = 0.f;
#pragma unroll
        for (int d = 0; d < 8; ++d) {
            float4 v = *reinterpret_cast<const float4*>(xp + d * 4);
            int w0 = __builtin_amdgcn_cvt_pk_fp8_f32(v.x, v.y, 0, false);
            w0 = __builtin_amdgcn_cvt_pk_fp8_f32(v.z, v.w, w0, true);
            afrag[t].d[d] = w0;
            s += v.x * v.x + v.y * v.y + v.z * v.z + v.w * v.w;
        }
        s += __shfl_xor(s, 16, 64);
        s += __shfl_xor(s, 32, 64);
        if (half == 0 && q == 0) s_xn[pairw * 64 + t * 16 + m] = s;
    }
    __syncthreads();   // s_pn + s_xn visible; only barrier before epilogue

    // runmax tracks max_p (x.p - ||p||^2/2); d2 = ||x||^2 - 2*max at the end.
    float runmax[4][4];
#pragma unroll
    for (int t = 0; t < 4; ++t)
#pragma unroll
        for (int r = 0; r < 4; ++r) runmax[t][r] = -1e30f;

    const uint4* bsw = reinterpret_cast<const uint4*>(ptsf8);
    const int T0 = half * 64;      // this wave's 64-tile half of the points

    BFrag bA, bB, bC, bD;
    float pnA, pnB, pnC, pnD;

#define LOADT(gT, buf, pnh) do {                       \
        buf.u4[0] = bsw[(gT) * 128 + lane];            \
        buf.u4[1] = bsw[(gT) * 128 + 64 + lane];       \
        pnh = s_pn[(gT) * 16 + m];                     \
    } while (0)

    auto compute = [&](const BFrag& buf, float pnh) {
#pragma unroll
        for (int t = 0; t < 4; ++t) {
            f32x4 acc = {pnh, pnh, pnh, pnh};   // C = -||p||^2/2 broadcast
            acc = __builtin_amdgcn_mfma_scale_f32_16x16x128_f8f6f4(
                afrag[t].v, buf.v, acc, 0, 0, 0, 0x7F7F7F7F, 0, 0x7F7F7F7F);
#pragma unroll
            for (int r = 0; r < 4; ++r)
                runmax[t][r] = fmaxf(runmax[t][r], acc[r]);
        }
    };

    // depth-2 register prefetch, 4 statically-named buffers (no dyn indexing)
    LOADT(T0 + 0, bA, pnA);
    LOADT(T0 + 1, bB, pnB);
    for (int T = 0; T < 64; T += 4) {
        LOADT(T0 + T + 2, bC, pnC);
        compute(bA, pnA);
        LOADT(T0 + T + 3, bD, pnD);
        compute(bB, pnB);
        if (T + 4 < 64) LOADT(T0 + T + 4, bA, pnA);
        compute(bC, pnC);
        if (T + 5 < 64) LOADT(T0 + T + 5, bB, pnB);
        compute(bD, pnD);
    }
#undef LOADT

    // C/D layout: col = m (point), row_local = q*4 + r (x-row).
    // Max-reduce over the 16 cols, store per-half partial to LDS.
#pragma unroll
    for (int t = 0; t < 4; ++t) {
#pragma unroll
        for (int r = 0; r < 4; ++r) {
            float v = runmax[t][r];
            v = fmaxf(v, __shfl_xor(v, 1, 64));
            v = fmaxf(v, __shfl_xor(v, 2, 64));
            v = fmaxf(v, __shfl_xor(v, 4, 64));
            v = fmaxf(v, __shfl_xor(v, 8, 64));
            if (m == 0)
                s_red[half][pairw * 64 + t * 16 + q * 4 + r] = v;
        }
    }
    __syncthreads();

    if (tid < 128) {
        float vmax  = fmaxf(s_red[0][tid], s_red[1][tid]);
        float d2    = fmaxf(fmaf(-2.f, vmax, s_xn[tid]), 0.f);
        float br    = beta_raw[0];
        float beta  = log1pf(expf(br));
        float alpha = -beta * LOG1000F;
        float z     = (d2 + alpha) / beta;
        out[(size_t)blockIdx.x * 128 + tid] = 1.f / (1.f + expf(-z));
    }
}

extern "C" void kernel_launch(void* const* d_in, const int* in_sizes, int n_in,
                              void* d_out, int out_size, void* d_ws, size_t ws_size,
                              hipStream_t stream) {
    const float* x        = (const float*)d_in[0];
    const float* pts      = (const float*)d_in[1];
    const float* beta_raw = (const float*)d_in[2];
    float* out            = (float*)d_out;

    unsigned char* ptsf8 = (unsigned char*)d_ws;                    // 256 KB
    float* pnorm = (float*)((char*)d_ws + (size_t)NPTS * DIMS);     // 8 KB

    prep_points_kernel<<<NPTS / 4, 256, 0, stream>>>(pts, ptsf8, pnorm);
    distnet_main_kernel<<<NROWS / 128, 256, 0, stream>>>(x, ptsf8, pnorm,
                                                         beta_raw, out);
}